// Round 23
// baseline (30.891 us; speedup 1.0000x reference)
//
#include <hip/hip_runtime.h>
#include <math.h>

#define B_ 16
#define T_ 2048
#define N_ 8
#define D_ 512
#define LP2 264         // LDS row pitch for 256-col tile (words)

// DIAGNOSTIC ROUND: prep launched TWICE (idempotent — all writes are pure
// functions of the fixed inputs), main once. Steady-state:
//   dur23 = 2*prep + main;  R22: prep + main = 26.0  =>  prep = dur23 - 26.
// Kernel bodies byte-identical to R22 (passing, 26.0 us).

// -pi/1024 ( = -2*pi/2048 )
#define NEG_W0 (-3.0679615757712823e-3f)
// -2*ln(10000)/512
#define NEG_LDIV (-0.035977892078031555f)

typedef __attribute__((ext_vector_type(8))) short bf16x8;
typedef __attribute__((ext_vector_type(4))) float f32x4;

// fp32 -> bf16 (round-to-nearest-even)
static __device__ __forceinline__ short f2bf(float f) {
  unsigned int u = __float_as_uint(f);
  unsigned int r = u + 0x7FFFu + ((u >> 16) & 1u);
  return (short)(r >> 16);
}

__global__ __launch_bounds__(512) void prep_kernel(
    const float* __restrict__ x, const int* __restrict__ xmark,
    const float* __restrict__ convw, float* __restrict__ pmax,
    float* __restrict__ nyqS, float* __restrict__ tab,
    short* __restrict__ amat, short* __restrict__ xbf,
    short* __restrict__ cnt) {
  __shared__ __align__(16) float2 zs[1088];   // 1024 + pad(i>>4)
  __shared__ __align__(16) float2 tws[544];   // 512 + pad
  __shared__ float red[8];
  int tid = threadIdx.x;
  int blk = blockIdx.x;

  if (blk < 128) {
    // ---- fft role (R20-validated) ----
    int bn = blk;
    int b = bn >> 3, n = bn & 7;
    const float* xb = x + (size_t)b * (T_ * N_) + n;

    {  // twiddle table: tws[k] = e^{-2pi i k/1024}
      float ss, cc;
      sincosf((float)tid * (2.0f * NEG_W0), &ss, &cc);
      tws[tid + (tid >> 4)] = make_float2(cc, ss);
    }
#pragma unroll
    for (int u = 0; u < 2; ++u) {   // load, bit-reversed placement
      int tau = tid + u * 512;
      float re = xb[(2 * tau) * 8];
      float im = xb[(2 * tau + 1) * 8];
      int p = __brev(tau) >> 22;    // 10-bit reversal
      zs[p + (p >> 4)] = make_float2(re, im);
    }
    __syncthreads();

#pragma unroll
    for (int s = 1; s <= 10; ++s) { // radix-2 DIT stages
      int half = 1 << (s - 1);
      int idx = tid & (half - 1);
      int grp = tid >> (s - 1);
      int p0 = grp * (half << 1) + idx;
      int p1 = p0 + half;
      int ti = idx << (10 - s);
      float2 tw = tws[ti + (ti >> 4)];
      float2 a = zs[p0 + (p0 >> 4)];
      float2 bv = zs[p1 + (p1 >> 4)];
      float tr = bv.x * tw.x - bv.y * tw.y;
      float tq = fmaf(bv.x, tw.y, bv.y * tw.x);
      zs[p1 + (p1 >> 4)] = make_float2(a.x - tr, a.y - tq);
      zs[p0 + (p0 >> 4)] = make_float2(a.x + tr, a.y + tq);
      __syncthreads();
    }

    // untangle: thread j covers bins k=j and k=1024-j
    int j = tid;
    int jm = (1024 - j) & 1023;
    float2 A = zs[j + (j >> 4)];
    float2 Bv = zs[jm + (jm >> 4)];
    float u = A.x - Bv.x, v = A.y + Bv.y;
    float Ere = 0.5f * (A.x + Bv.x), Eim = 0.5f * (A.y - Bv.y);
    float Ore = 0.5f * v, Oim = -0.5f * u;
    float cw, sw;
    sincosf((float)j * NEG_W0, &sw, &cw);
    float Gr = Ere + cw * Ore - sw * Oim;       // X_j
    float Gi = Eim + cw * Oim + sw * Ore;
    float P = fmaf(Gr, Gr, Gi * Gi);
    float Gpr = Ere - cw * Ore + sw * Oim;      // X_{1024-j}
    float Gpi = -Eim + cw * Oim + sw * Ore;
    float P2;
    if (j == 0) {
      nyqS[bn] = Gpr;                           // X_1024 (excluded from max)
      float2 Am = zs[512 + (512 >> 4)];         // k=512: X = conj(Z_512)
      P2 = fmaf(Am.x, Am.x, Am.y * Am.y);
    } else {
      P2 = fmaf(Gpr, Gpr, Gpi * Gpi);
    }
    P = fmaxf(P, P2);
#pragma unroll
    for (int off = 32; off > 0; off >>= 1) P = fmaxf(P, __shfl_down(P, off));
    if ((tid & 63) == 0) red[tid >> 6] = P;
    __syncthreads();
    if (tid == 0) {
      float mx = red[0];
#pragma unroll
      for (int k = 1; k < 8; ++k) mx = fmaxf(mx, red[k]);
      pmax[bn] = mx;                            // single unconditional writer
    }
    return;
  }

  int j = blk - 128;
  if (j < 128) {                        // ---- FET tabgen (full coverage) ----
    int base = j * 2048 + tid * 4;      // 128 blk x 512 thr x 4 = 262144 f4
#pragma unroll
    for (int u = 0; u < 4; ++u) {
      int idx = base + u;
      int t = idx >> 7;
      int d4 = idx & 127;
      float ft = (float)t;
      float dv0 = expf((float)(d4 * 2) * NEG_LDIV);
      float dv1 = expf((float)(d4 * 2 + 1) * NEG_LDIV);
      f32x4 v;
      float s0, c0, s1, c1;
      sincosf(ft * dv0, &s0, &c0);
      sincosf(ft * dv1, &s1, &c1);
      v[0] = s0; v[1] = c0; v[2] = s1; v[3] = c1;
      *(f32x4*)(tab + (size_t)idx * 4) = v;
    }
  } else if (j < 192) {                 // ---- xbf + cnt rows ----
    int r = (j - 128) * 512 + tid;      // r = b*T + t, 0..32767
    const float4* xr = (const float4*)(x + (size_t)r * 8);
    float4 lo = xr[0], hi = xr[1];
    bf16x8 v;
    v[0] = f2bf(lo.x); v[1] = f2bf(lo.y); v[2] = f2bf(lo.z); v[3] = f2bf(lo.w);
    v[4] = f2bf(hi.x); v[5] = f2bf(hi.y); v[6] = f2bf(hi.z); v[7] = f2bf(hi.w);
    *(bf16x8*)(xbf + (size_t)r * 8) = v;
    int4 mk = *(const int4*)(xmark + (size_t)r * 4);
    bf16x8 cv;
#pragma unroll
    for (int p = 0; p < 8; ++p) {
      int cc = (mk.x == p) + (mk.y == p) + (mk.z == p) + (mk.w == p);
      cv[p] = f2bf((float)cc);
    }
    *(bf16x8*)(cnt + (size_t)r * 8) = cv;
  } else {                              // ---- amat ----
    int d = tid;                        // 0..511
    short row[32];
#pragma unroll
    for (int kk = 0; kk < 24; ++kk) {
      int g = kk >> 3, n = kk & 7;      // A[d][g*8+n] = W[d][n][k=g]
      row[kk] = f2bf(convw[d * 24 + n * 3 + g]);
    }
    float divv = expf((float)(d >> 1) * NEG_LDIV);
    float s1, c1;
    sincosf(divv, &s1, &c1);
    int odd = d & 1;
    row[24] = f2bf(odd ? 1.f : 0.f);
    float ps = s1, pc = c1;
    row[25] = f2bf(odd ? pc : ps);
#pragma unroll
    for (int p = 2; p < 7; ++p) {
      float ns = fmaf(ps, c1, pc * s1);
      float nc = fmaf(pc, c1, -ps * s1);
      ps = ns; pc = nc;
      row[24 + p] = f2bf(odd ? pc : ps);
    }
    row[31] = 0;                        // marks < 7
#pragma unroll
    for (int q = 0; q < 4; ++q)
      *(bf16x8*)(amat + d * 32 + q * 8) = *(bf16x8*)&row[q * 8];
  }
}

// ---- main (byte-identical to R22) ----
__global__ __launch_bounds__(256, 8) void main_kernel(
    const short* __restrict__ amat, const short* __restrict__ xbf,
    const short* __restrict__ cnt, const float* __restrict__ tab,
    const float* __restrict__ pmax, const float* __restrict__ nyqS,
    float* __restrict__ out) {
  __shared__ __align__(16) float lds[16 * LP2];
  int tid = threadIdx.x;
  int lane = tid & 63;
  int w = tid >> 6;            // wave 0..3
  int c = lane & 15;           // t-col / A d-row
  int g = lane >> 4;           // k-slot group / C d-subgroup
  int blk = blockIdx.x;
  int ttile = blk & 127;
  int rest = blk >> 7;         // 0..15
  int bg = rest & 7;           // batches bg*2, bg*2+1
  int dhalf = rest >> 3;       // d in [dhalf*256, dhalf*256+256)
  int t0 = ttile * 16;
  int dbase = dhalf * 256;

  float w1v[2], w0v[2];
#pragma unroll
  for (int j = 0; j < 2; ++j) {
    int b = bg * 2 + j;
    int m = 0;
#pragma unroll
    for (int nn = 0; nn < 8; ++nn) {
      int bn = b * 8 + nn;
      float mx = pmax[bn];
      float S = nyqS[bn];
      if (S * S > mx) ++m;
    }
    w1v[j] = (float)(8 - m) * 0.125f;
    w0v[j] = (float)m * 0.125f;
  }

  f32x4 fet[4];
#pragma unroll
  for (int q = 0; q < 4; ++q) {
    int dq = dbase + (w * 4 + q) * 16;
    fet[q] = *(const f32x4*)(tab + (size_t)(t0 + c) * D_ + dq + g * 4);
  }

  const f32x4 zac = {0.f, 0.f, 0.f, 0.f};
#pragma unroll
  for (int j = 0; j < 2; ++j) {
    int b = bg * 2 + j;
    bf16x8 bfrag;
    if (g < 3) {
      int row = (t0 + c + g - 1) & (T_ - 1);    // circular pad
      bfrag = *(const bf16x8*)(xbf + ((size_t)b * T_ + row) * 8);
    } else {
      bfrag = *(const bf16x8*)(cnt + ((size_t)b * T_ + t0 + c) * 8);
    }
    float w1 = w1v[j], w0 = w0v[j];
#pragma unroll
    for (int q = 0; q < 4; ++q) {
      int dq = dbase + (w * 4 + q) * 16;
      bf16x8 afrag = *(const bf16x8*)(amat + (size_t)(dq + c) * 32 + g * 8);
      f32x4 acc = __builtin_amdgcn_mfma_f32_16x16x32_bf16(
          afrag, bfrag, zac, 0, 0, 0);
      f32x4 ov;
      ov[0] = fmaf(w1, fet[q][0], acc[0]);
      ov[1] = fmaf(w1, fet[q][1], acc[1]) + w0;
      ov[2] = fmaf(w1, fet[q][2], acc[2]);
      ov[3] = fmaf(w1, fet[q][3], acc[3]) + w0;
      *(f32x4*)(lds + c * LP2 + (w * 4 + q) * 16 + g * 4) = ov;
    }
    __syncthreads();
    float* obase = out + ((size_t)b * T_ + t0) * D_ + dbase;
#pragma unroll
    for (int r = 0; r < 4; ++r) {
      int e = r * 1024 + tid * 4;               // element offset in tile
      int trow = e >> 8, col = e & 255;
      f32x4 v = *(const f32x4*)(lds + trow * LP2 + col);
      *(f32x4*)(obase + trow * D_ + col) = v;
    }
    if (j == 0) __syncthreads();                // last iter: no LDS reuse
  }
}

extern "C" void kernel_launch(void* const* d_in, const int* in_sizes, int n_in,
                              void* d_out, int out_size, void* d_ws, size_t ws_size,
                              hipStream_t stream) {
  const float* x = (const float*)d_in[0];
  const int* xmark = (const int*)d_in[1];
  const float* convw = (const float*)d_in[2];
  float* out = (float*)d_out;

  char* ws = (char*)d_ws;
  float* pmax = (float*)ws;                            // 128 f
  float* nyqS = (float*)(ws + 2048);                   // 128 f
  float* tab = (float*)(ws + 8192);                    // 4 MB FET
  short* amat = (short*)(ws + 8192 + 4194304);         // 32 KB
  short* xbf = (short*)(ws + 8192 + 4194304 + 32768);  // 512 KB
  short* cnt = (short*)(ws + 8192 + 4194304 + 32768 + 524288);  // 512 KB

  // DIAGNOSTIC: prep twice (idempotent) -> prep_wall = dur23 - 26.0
  prep_kernel<<<321, 512, 0, stream>>>(x, xmark, convw, pmax, nyqS, tab,
                                       amat, xbf, cnt);
  prep_kernel<<<321, 512, 0, stream>>>(x, xmark, convw, pmax, nyqS, tab,
                                       amat, xbf, cnt);
  main_kernel<<<2048, 256, 0, stream>>>(amat, xbf, cnt, tab, pmax, nyqS, out);
}

// Round 24
// 27.710 us; speedup vs baseline: 1.1148x; 1.1148x over previous
//
#include <hip/hip_runtime.h>
#include <math.h>

#define B_ 16
#define T_ 2048
#define N_ 8
#define D_ 512
#define LP2 264         // LDS row pitch for 256-col tile (words)

// -pi/1024 ( = -2*pi/2048 )
#define NEG_W0 (-3.0679615757712823e-3f)
// -2*ln(10000)/512
#define NEG_LDIV (-0.035977892078031555f)

typedef __attribute__((ext_vector_type(8))) short bf16x8;
typedef __attribute__((ext_vector_type(4))) float f32x4;

// fp32 -> bf16 (round-to-nearest-even)
static __device__ __forceinline__ short f2bf(float f) {
  unsigned int u = __float_as_uint(f);
  unsigned int r = u + 0x7FFFu + ((u >> 16) & 1u);
  return (short)(r >> 16);
}

// ws layout (byte offsets): [0,512) pmax[128]; [2048,2560) nyqS[128];
// [8K,8K+4M) FET tab f32[2048][512]; +4M: amat bf16[512][32] (32 KB);
// xbf bf16[16][2048][8] (512 KB); cnt bf16[16][2048][8] (512 KB).
// All rewritten unconditionally every call.

// ---- prep (byte-identical to R22; measured wall 4.9 us via R23) ----
__global__ __launch_bounds__(512) void prep_kernel(
    const float* __restrict__ x, const int* __restrict__ xmark,
    const float* __restrict__ convw, float* __restrict__ pmax,
    float* __restrict__ nyqS, float* __restrict__ tab,
    short* __restrict__ amat, short* __restrict__ xbf,
    short* __restrict__ cnt) {
  __shared__ __align__(16) float2 zs[1088];   // 1024 + pad(i>>4)
  __shared__ __align__(16) float2 tws[544];   // 512 + pad
  __shared__ float red[8];
  int tid = threadIdx.x;
  int blk = blockIdx.x;

  if (blk < 128) {
    // ---- fft role (R20-validated radix-2 DIT of z = x_even + i*x_odd) ----
    int bn = blk;
    int b = bn >> 3, n = bn & 7;
    const float* xb = x + (size_t)b * (T_ * N_) + n;

    {  // twiddle table: tws[k] = e^{-2pi i k/1024}
      float ss, cc;
      sincosf((float)tid * (2.0f * NEG_W0), &ss, &cc);
      tws[tid + (tid >> 4)] = make_float2(cc, ss);
    }
#pragma unroll
    for (int u = 0; u < 2; ++u) {   // load, bit-reversed placement
      int tau = tid + u * 512;
      float re = xb[(2 * tau) * 8];
      float im = xb[(2 * tau + 1) * 8];
      int p = __brev(tau) >> 22;    // 10-bit reversal
      zs[p + (p >> 4)] = make_float2(re, im);
    }
    __syncthreads();

#pragma unroll
    for (int s = 1; s <= 10; ++s) { // radix-2 DIT stages
      int half = 1 << (s - 1);
      int idx = tid & (half - 1);
      int grp = tid >> (s - 1);
      int p0 = grp * (half << 1) + idx;
      int p1 = p0 + half;
      int ti = idx << (10 - s);
      float2 tw = tws[ti + (ti >> 4)];
      float2 a = zs[p0 + (p0 >> 4)];
      float2 bv = zs[p1 + (p1 >> 4)];
      float tr = bv.x * tw.x - bv.y * tw.y;
      float tq = fmaf(bv.x, tw.y, bv.y * tw.x);
      zs[p1 + (p1 >> 4)] = make_float2(a.x - tr, a.y - tq);
      zs[p0 + (p0 >> 4)] = make_float2(a.x + tr, a.y + tq);
      __syncthreads();
    }

    // untangle: thread j covers bins k=j and k=1024-j
    int j = tid;
    int jm = (1024 - j) & 1023;
    float2 A = zs[j + (j >> 4)];
    float2 Bv = zs[jm + (jm >> 4)];
    float u = A.x - Bv.x, v = A.y + Bv.y;
    float Ere = 0.5f * (A.x + Bv.x), Eim = 0.5f * (A.y - Bv.y);
    float Ore = 0.5f * v, Oim = -0.5f * u;
    float cw, sw;
    sincosf((float)j * NEG_W0, &sw, &cw);
    float Gr = Ere + cw * Ore - sw * Oim;       // X_j
    float Gi = Eim + cw * Oim + sw * Ore;
    float P = fmaf(Gr, Gr, Gi * Gi);
    float Gpr = Ere - cw * Ore + sw * Oim;      // X_{1024-j}
    float Gpi = -Eim + cw * Oim + sw * Ore;
    float P2;
    if (j == 0) {
      nyqS[bn] = Gpr;                           // X_1024 (excluded from max)
      float2 Am = zs[512 + (512 >> 4)];         // k=512: X = conj(Z_512)
      P2 = fmaf(Am.x, Am.x, Am.y * Am.y);
    } else {
      P2 = fmaf(Gpr, Gpr, Gpi * Gpi);
    }
    P = fmaxf(P, P2);
#pragma unroll
    for (int off = 32; off > 0; off >>= 1) P = fmaxf(P, __shfl_down(P, off));
    if ((tid & 63) == 0) red[tid >> 6] = P;
    __syncthreads();
    if (tid == 0) {
      float mx = red[0];
#pragma unroll
      for (int k = 1; k < 8; ++k) mx = fmaxf(mx, red[k]);
      pmax[bn] = mx;                            // single unconditional writer
    }
    return;
  }

  int j = blk - 128;
  if (j < 128) {                        // ---- FET tabgen (full coverage) ----
    int base = j * 2048 + tid * 4;      // 128 blk x 512 thr x 4 = 262144 f4
#pragma unroll
    for (int u = 0; u < 4; ++u) {
      int idx = base + u;
      int t = idx >> 7;
      int d4 = idx & 127;
      float ft = (float)t;
      float dv0 = expf((float)(d4 * 2) * NEG_LDIV);
      float dv1 = expf((float)(d4 * 2 + 1) * NEG_LDIV);
      f32x4 v;
      float s0, c0, s1, c1;
      sincosf(ft * dv0, &s0, &c0);
      sincosf(ft * dv1, &s1, &c1);
      v[0] = s0; v[1] = c0; v[2] = s1; v[3] = c1;
      *(f32x4*)(tab + (size_t)idx * 4) = v;
    }
  } else if (j < 192) {                 // ---- xbf + cnt rows ----
    int r = (j - 128) * 512 + tid;      // r = b*T + t, 0..32767
    const float4* xr = (const float4*)(x + (size_t)r * 8);
    float4 lo = xr[0], hi = xr[1];
    bf16x8 v;
    v[0] = f2bf(lo.x); v[1] = f2bf(lo.y); v[2] = f2bf(lo.z); v[3] = f2bf(lo.w);
    v[4] = f2bf(hi.x); v[5] = f2bf(hi.y); v[6] = f2bf(hi.z); v[7] = f2bf(hi.w);
    *(bf16x8*)(xbf + (size_t)r * 8) = v;
    int4 mk = *(const int4*)(xmark + (size_t)r * 4);
    bf16x8 cv;
#pragma unroll
    for (int p = 0; p < 8; ++p) {
      int cc = (mk.x == p) + (mk.y == p) + (mk.z == p) + (mk.w == p);
      cv[p] = f2bf((float)cc);
    }
    *(bf16x8*)(cnt + (size_t)r * 8) = cv;
  } else {                              // ---- amat ----
    int d = tid;                        // 0..511
    short row[32];
#pragma unroll
    for (int kk = 0; kk < 24; ++kk) {
      int g = kk >> 3, n = kk & 7;      // A[d][g*8+n] = W[d][n][k=g]
      row[kk] = f2bf(convw[d * 24 + n * 3 + g]);
    }
    float divv = expf((float)(d >> 1) * NEG_LDIV);
    float s1, c1;
    sincosf(divv, &s1, &c1);
    int odd = d & 1;
    row[24] = f2bf(odd ? 1.f : 0.f);
    float ps = s1, pc = c1;
    row[25] = f2bf(odd ? pc : ps);
#pragma unroll
    for (int p = 2; p < 7; ++p) {
      float ns = fmaf(ps, c1, pc * s1);
      float nc = fmaf(pc, c1, -ps * s1);
      ps = ns; pc = nc;
      row[24 + p] = f2bf(odd ? pc : ps);
    }
    row[31] = 0;                        // marks < 7
#pragma unroll
    for (int q = 0; q < 4; ++q)
      *(bf16x8*)(amat + d * 32 + q * 8) = *(bf16x8*)&row[q * 8];
  }
}

// ---- main: BARRIER-FREE. Wave-private LDS repack: wave w owns cols
// [w*64, w*64+64) of the 16x256 tile for both the MFMA-output writes and
// the store-phase reads -> no cross-wave dependency -> zero __syncthreads.
// Batch-2 compute overlaps batch-1 store drain (no mid-block vmcnt(0)),
// blocks drift out of phase -> store pipe stays fed (fix for R23's finding:
// main wall 21.1 us vs 11.3 us throughput due to barrier-synced bursts).
// Stores: 4x256B contiguous segments per instruction (16 lanes x 16 B).
__global__ __launch_bounds__(256, 8) void main_kernel(
    const short* __restrict__ amat, const short* __restrict__ xbf,
    const short* __restrict__ cnt, const float* __restrict__ tab,
    const float* __restrict__ pmax, const float* __restrict__ nyqS,
    float* __restrict__ out) {
  __shared__ __align__(16) float lds[16 * LP2];
  int tid = threadIdx.x;
  int lane = tid & 63;
  int w = tid >> 6;            // wave 0..3 -> cols [w*64, w*64+64)
  int c = lane & 15;           // t-col / A d-row (compute phase)
  int g = lane >> 4;           // k-slot group (compute phase)
  int lr = lane >> 4;          // row-subgroup (store phase)
  int lc = lane & 15;          // col-quad (store phase)
  int blk = blockIdx.x;
  int ttile = blk & 127;
  int rest = blk >> 7;         // 0..15
  int bg = rest & 7;           // batches bg*2, bg*2+1
  int dhalf = rest >> 3;       // d in [dhalf*256, dhalf*256+256)
  int t0 = ttile * 16;
  int dbase = dhalf * 256;

  float w1v[2], w0v[2];
#pragma unroll
  for (int j = 0; j < 2; ++j) {
    int b = bg * 2 + j;
    int m = 0;
#pragma unroll
    for (int nn = 0; nn < 8; ++nn) {
      int bn = b * 8 + nn;
      float mx = pmax[bn];
      float S = nyqS[bn];
      if (S * S > mx) ++m;
    }
    w1v[j] = (float)(8 - m) * 0.125f;
    w0v[j] = (float)m * 0.125f;
  }

  // fet persistent in regs; both batches' bfrag hoisted (independent loads)
  f32x4 fet[4];
#pragma unroll
  for (int q = 0; q < 4; ++q) {
    int dq = dbase + (w * 4 + q) * 16;
    fet[q] = *(const f32x4*)(tab + (size_t)(t0 + c) * D_ + dq + g * 4);
  }
  bf16x8 bfr[2];
#pragma unroll
  for (int j = 0; j < 2; ++j) {
    int b = bg * 2 + j;
    if (g < 3) {
      int row = (t0 + c + g - 1) & (T_ - 1);    // circular pad
      bfr[j] = *(const bf16x8*)(xbf + ((size_t)b * T_ + row) * 8);
    } else {
      bfr[j] = *(const bf16x8*)(cnt + ((size_t)b * T_ + t0 + c) * 8);
    }
  }

  const f32x4 zac = {0.f, 0.f, 0.f, 0.f};
#pragma unroll
  for (int j = 0; j < 2; ++j) {
    int b = bg * 2 + j;
    float w1 = w1v[j], w0 = w0v[j];
#pragma unroll
    for (int q = 0; q < 4; ++q) {
      int dq = dbase + (w * 4 + q) * 16;
      bf16x8 afrag = *(const bf16x8*)(amat + (size_t)(dq + c) * 32 + g * 8);
      f32x4 acc = __builtin_amdgcn_mfma_f32_16x16x32_bf16(
          afrag, bfr[j], zac, 0, 0, 0);
      f32x4 ov;
      ov[0] = fmaf(w1, fet[q][0], acc[0]);
      ov[1] = fmaf(w1, fet[q][1], acc[1]) + w0;
      ov[2] = fmaf(w1, fet[q][2], acc[2]);
      ov[3] = fmaf(w1, fet[q][3], acc[3]) + w0;
      *(f32x4*)(lds + c * LP2 + (w * 4 + q) * 16 + g * 4) = ov;
    }
    // wave-private store phase (reads ONLY this wave's cols; lgkmcnt-ordered
    // within the wave by the compiler; NO barrier)
    float* obase = out + ((size_t)b * T_ + t0) * D_ + dbase + w * 64;
#pragma unroll
    for (int r = 0; r < 4; ++r) {
      int row = r * 4 + lr;
      f32x4 v = *(const f32x4*)(lds + row * LP2 + w * 64 + lc * 4);
      *(f32x4*)(obase + (size_t)row * D_ + lc * 4) = v;
    }
  }
}

extern "C" void kernel_launch(void* const* d_in, const int* in_sizes, int n_in,
                              void* d_out, int out_size, void* d_ws, size_t ws_size,
                              hipStream_t stream) {
  const float* x = (const float*)d_in[0];
  const int* xmark = (const int*)d_in[1];
  const float* convw = (const float*)d_in[2];
  float* out = (float*)d_out;

  char* ws = (char*)d_ws;
  float* pmax = (float*)ws;                            // 128 f
  float* nyqS = (float*)(ws + 2048);                   // 128 f
  float* tab = (float*)(ws + 8192);                    // 4 MB FET
  short* amat = (short*)(ws + 8192 + 4194304);         // 32 KB
  short* xbf = (short*)(ws + 8192 + 4194304 + 32768);  // 512 KB
  short* cnt = (short*)(ws + 8192 + 4194304 + 32768 + 524288);  // 512 KB

  prep_kernel<<<321, 512, 0, stream>>>(x, xmark, convw, pmax, nyqS, tab,
                                       amat, xbf, cnt);
  main_kernel<<<2048, 256, 0, stream>>>(amat, xbf, cnt, tab, pmax, nyqS, out);
}

// Round 25
// 25.982 us; speedup vs baseline: 1.1890x; 1.0665x over previous
//
#include <hip/hip_runtime.h>
#include <math.h>

#define B_ 16
#define T_ 2048
#define N_ 8
#define D_ 512
#define LP2 264         // LDS row pitch for 256-col tile (words)

// -pi/1024 ( = -2*pi/2048 )
#define NEG_W0 (-3.0679615757712823e-3f)
// -2*ln(10000)/512
#define NEG_LDIV (-0.035977892078031555f)

typedef __attribute__((ext_vector_type(8))) short bf16x8;
typedef __attribute__((ext_vector_type(4))) float f32x4;

// fp32 -> bf16 (round-to-nearest-even)
static __device__ __forceinline__ short f2bf(float f) {
  unsigned int u = __float_as_uint(f);
  unsigned int r = u + 0x7FFFu + ((u >> 16) & 1u);
  return (short)(r >> 16);
}

// ws layout (byte offsets): [0,512) pmax[128]; [2048,2560) nyqS[128];
// [8K,8K+4M) FET tab f32[2048][512]; +4M: amat bf16[512][32] (32 KB);
// xbf bf16[16][2048][8] (512 KB); cnt bf16[16][2048][8] (512 KB).
// All rewritten unconditionally every call. (Byte-identical to R22 — the
// measured best at 26.0 us; R24's barrier-free variant regressed.)

__global__ __launch_bounds__(512) void prep_kernel(
    const float* __restrict__ x, const int* __restrict__ xmark,
    const float* __restrict__ convw, float* __restrict__ pmax,
    float* __restrict__ nyqS, float* __restrict__ tab,
    short* __restrict__ amat, short* __restrict__ xbf,
    short* __restrict__ cnt) {
  __shared__ __align__(16) float2 zs[1088];   // 1024 + pad(i>>4)
  __shared__ __align__(16) float2 tws[544];   // 512 + pad
  __shared__ float red[8];
  int tid = threadIdx.x;
  int blk = blockIdx.x;

  if (blk < 128) {
    // ---- fft role: complex 1024-pt radix-2 DIT of z = x_even + i*x_odd ----
    int bn = blk;
    int b = bn >> 3, n = bn & 7;
    const float* xb = x + (size_t)b * (T_ * N_) + n;

    {  // twiddle table: tws[k] = e^{-2pi i k/1024}
      float ss, cc;
      sincosf((float)tid * (2.0f * NEG_W0), &ss, &cc);
      tws[tid + (tid >> 4)] = make_float2(cc, ss);
    }
#pragma unroll
    for (int u = 0; u < 2; ++u) {   // load, bit-reversed placement
      int tau = tid + u * 512;
      float re = xb[(2 * tau) * 8];
      float im = xb[(2 * tau + 1) * 8];
      int p = __brev(tau) >> 22;    // 10-bit reversal
      zs[p + (p >> 4)] = make_float2(re, im);
    }
    __syncthreads();

#pragma unroll
    for (int s = 1; s <= 10; ++s) { // radix-2 DIT stages
      int half = 1 << (s - 1);
      int idx = tid & (half - 1);
      int grp = tid >> (s - 1);
      int p0 = grp * (half << 1) + idx;
      int p1 = p0 + half;
      int ti = idx << (10 - s);
      float2 tw = tws[ti + (ti >> 4)];
      float2 a = zs[p0 + (p0 >> 4)];
      float2 bv = zs[p1 + (p1 >> 4)];
      float tr = bv.x * tw.x - bv.y * tw.y;
      float tq = fmaf(bv.x, tw.y, bv.y * tw.x);
      zs[p1 + (p1 >> 4)] = make_float2(a.x - tr, a.y - tq);
      zs[p0 + (p0 >> 4)] = make_float2(a.x + tr, a.y + tq);
      __syncthreads();
    }

    // untangle: thread j covers bins k=j and k=1024-j
    int j = tid;
    int jm = (1024 - j) & 1023;
    float2 A = zs[j + (j >> 4)];
    float2 Bv = zs[jm + (jm >> 4)];
    float u = A.x - Bv.x, v = A.y + Bv.y;
    float Ere = 0.5f * (A.x + Bv.x), Eim = 0.5f * (A.y - Bv.y);
    float Ore = 0.5f * v, Oim = -0.5f * u;
    float cw, sw;
    sincosf((float)j * NEG_W0, &sw, &cw);
    float Gr = Ere + cw * Ore - sw * Oim;       // X_j
    float Gi = Eim + cw * Oim + sw * Ore;
    float P = fmaf(Gr, Gr, Gi * Gi);
    float Gpr = Ere - cw * Ore + sw * Oim;      // X_{1024-j}
    float Gpi = -Eim + cw * Oim + sw * Ore;
    float P2;
    if (j == 0) {
      nyqS[bn] = Gpr;                           // X_1024 (excluded from max)
      float2 Am = zs[512 + (512 >> 4)];         // k=512: X = conj(Z_512)
      P2 = fmaf(Am.x, Am.x, Am.y * Am.y);
    } else {
      P2 = fmaf(Gpr, Gpr, Gpi * Gpi);
    }
    P = fmaxf(P, P2);
#pragma unroll
    for (int off = 32; off > 0; off >>= 1) P = fmaxf(P, __shfl_down(P, off));
    if ((tid & 63) == 0) red[tid >> 6] = P;
    __syncthreads();
    if (tid == 0) {
      float mx = red[0];
#pragma unroll
      for (int k = 1; k < 8; ++k) mx = fmaxf(mx, red[k]);
      pmax[bn] = mx;                            // single unconditional writer
    }
    return;
  }

  int j = blk - 128;
  if (j < 128) {                        // ---- FET tabgen (full coverage) ----
    int base = j * 2048 + tid * 4;      // 128 blk x 512 thr x 4 = 262144 f4
#pragma unroll
    for (int u = 0; u < 4; ++u) {
      int idx = base + u;
      int t = idx >> 7;
      int d4 = idx & 127;
      float ft = (float)t;
      float dv0 = expf((float)(d4 * 2) * NEG_LDIV);
      float dv1 = expf((float)(d4 * 2 + 1) * NEG_LDIV);
      f32x4 v;
      float s0, c0, s1, c1;
      sincosf(ft * dv0, &s0, &c0);
      sincosf(ft * dv1, &s1, &c1);
      v[0] = s0; v[1] = c0; v[2] = s1; v[3] = c1;
      *(f32x4*)(tab + (size_t)idx * 4) = v;
    }
  } else if (j < 192) {                 // ---- xbf + cnt rows ----
    int r = (j - 128) * 512 + tid;      // r = b*T + t, 0..32767
    const float4* xr = (const float4*)(x + (size_t)r * 8);
    float4 lo = xr[0], hi = xr[1];
    bf16x8 v;
    v[0] = f2bf(lo.x); v[1] = f2bf(lo.y); v[2] = f2bf(lo.z); v[3] = f2bf(lo.w);
    v[4] = f2bf(hi.x); v[5] = f2bf(hi.y); v[6] = f2bf(hi.z); v[7] = f2bf(hi.w);
    *(bf16x8*)(xbf + (size_t)r * 8) = v;
    int4 mk = *(const int4*)(xmark + (size_t)r * 4);
    bf16x8 cv;
#pragma unroll
    for (int p = 0; p < 8; ++p) {
      int cc = (mk.x == p) + (mk.y == p) + (mk.z == p) + (mk.w == p);
      cv[p] = f2bf((float)cc);
    }
    *(bf16x8*)(cnt + (size_t)r * 8) = cv;
  } else {                              // ---- amat ----
    int d = tid;                        // 0..511
    short row[32];
#pragma unroll
    for (int kk = 0; kk < 24; ++kk) {
      int g = kk >> 3, n = kk & 7;      // A[d][g*8+n] = W[d][n][k=g]
      row[kk] = f2bf(convw[d * 24 + n * 3 + g]);
    }
    float divv = expf((float)(d >> 1) * NEG_LDIV);
    float s1, c1;
    sincosf(divv, &s1, &c1);
    int odd = d & 1;
    row[24] = f2bf(odd ? 1.f : 0.f);
    float ps = s1, pc = c1;
    row[25] = f2bf(odd ? pc : ps);
#pragma unroll
    for (int p = 2; p < 7; ++p) {
      float ns = fmaf(ps, c1, pc * s1);
      float nc = fmaf(pc, c1, -ps * s1);
      ps = ns; pc = nc;
      row[24 + p] = f2bf(odd ? pc : ps);
    }
    row[31] = 0;                        // marks < 7
#pragma unroll
    for (int q = 0; q < 4; ++q)
      *(bf16x8*)(amat + d * 32 + q * 8) = *(bf16x8*)&row[q * 8];
  }
}

// ---- main (R22, best measured): 2048 x 256-thr blocks, 8 blocks/CU.
// Block = (ttile, batch-pair, d-half): 16 t-rows x 256 d x 2 batches.
// MFMA (conv slots 0..23 + temporal 24..31) -> LDS repack -> 4 x 4 KB
// sequential store rounds (1 KB contiguous per wave-instruction).
__global__ __launch_bounds__(256, 8) void main_kernel(
    const short* __restrict__ amat, const short* __restrict__ xbf,
    const short* __restrict__ cnt, const float* __restrict__ tab,
    const float* __restrict__ pmax, const float* __restrict__ nyqS,
    float* __restrict__ out) {
  __shared__ __align__(16) float lds[16 * LP2];
  int tid = threadIdx.x;
  int lane = tid & 63;
  int w = tid >> 6;            // wave 0..3
  int c = lane & 15;           // t-col / A d-row
  int g = lane >> 4;           // k-slot group / C d-subgroup
  int blk = blockIdx.x;
  int ttile = blk & 127;
  int rest = blk >> 7;         // 0..15
  int bg = rest & 7;           // batches bg*2, bg*2+1
  int dhalf = rest >> 3;       // d in [dhalf*256, dhalf*256+256)
  int t0 = ttile * 16;
  int dbase = dhalf * 256;

  float w1v[2], w0v[2];
#pragma unroll
  for (int j = 0; j < 2; ++j) {
    int b = bg * 2 + j;
    int m = 0;
#pragma unroll
    for (int nn = 0; nn < 8; ++nn) {
      int bn = b * 8 + nn;
      float mx = pmax[bn];
      float S = nyqS[bn];
      if (S * S > mx) ++m;
    }
    w1v[j] = (float)(8 - m) * 0.125f;
    w0v[j] = (float)m * 0.125f;
  }

  f32x4 fet[4];
#pragma unroll
  for (int q = 0; q < 4; ++q) {
    int dq = dbase + (w * 4 + q) * 16;
    fet[q] = *(const f32x4*)(tab + (size_t)(t0 + c) * D_ + dq + g * 4);
  }

  const f32x4 zac = {0.f, 0.f, 0.f, 0.f};
#pragma unroll
  for (int j = 0; j < 2; ++j) {
    int b = bg * 2 + j;
    bf16x8 bfrag;
    if (g < 3) {
      int row = (t0 + c + g - 1) & (T_ - 1);    // circular pad
      bfrag = *(const bf16x8*)(xbf + ((size_t)b * T_ + row) * 8);
    } else {
      bfrag = *(const bf16x8*)(cnt + ((size_t)b * T_ + t0 + c) * 8);
    }
    float w1 = w1v[j], w0 = w0v[j];
#pragma unroll
    for (int q = 0; q < 4; ++q) {
      int dq = dbase + (w * 4 + q) * 16;
      bf16x8 afrag = *(const bf16x8*)(amat + (size_t)(dq + c) * 32 + g * 8);
      f32x4 acc = __builtin_amdgcn_mfma_f32_16x16x32_bf16(
          afrag, bfrag, zac, 0, 0, 0);
      f32x4 ov;
      ov[0] = fmaf(w1, fet[q][0], acc[0]);
      ov[1] = fmaf(w1, fet[q][1], acc[1]) + w0;
      ov[2] = fmaf(w1, fet[q][2], acc[2]);
      ov[3] = fmaf(w1, fet[q][3], acc[3]) + w0;
      *(f32x4*)(lds + c * LP2 + (w * 4 + q) * 16 + g * 4) = ov;
    }
    __syncthreads();
    float* obase = out + ((size_t)b * T_ + t0) * D_ + dbase;
#pragma unroll
    for (int r = 0; r < 4; ++r) {
      int e = r * 1024 + tid * 4;               // element offset in tile
      int trow = e >> 8, col = e & 255;
      f32x4 v = *(const f32x4*)(lds + trow * LP2 + col);
      *(f32x4*)(obase + trow * D_ + col) = v;
    }
    if (j == 0) __syncthreads();                // last iter: no LDS reuse
  }
}

extern "C" void kernel_launch(void* const* d_in, const int* in_sizes, int n_in,
                              void* d_out, int out_size, void* d_ws, size_t ws_size,
                              hipStream_t stream) {
  const float* x = (const float*)d_in[0];
  const int* xmark = (const int*)d_in[1];
  const float* convw = (const float*)d_in[2];
  float* out = (float*)d_out;

  char* ws = (char*)d_ws;
  float* pmax = (float*)ws;                            // 128 f
  float* nyqS = (float*)(ws + 2048);                   // 128 f
  float* tab = (float*)(ws + 8192);                    // 4 MB FET
  short* amat = (short*)(ws + 8192 + 4194304);         // 32 KB
  short* xbf = (short*)(ws + 8192 + 4194304 + 32768);  // 512 KB
  short* cnt = (short*)(ws + 8192 + 4194304 + 32768 + 524288);  // 512 KB

  prep_kernel<<<321, 512, 0, stream>>>(x, xmark, convw, pmax, nyqS, tab,
                                       amat, xbf, cnt);
  main_kernel<<<2048, 256, 0, stream>>>(amat, xbf, cnt, tab, pmax, nyqS, out);
}